// Round 1
// baseline (879.312 us; speedup 1.0000x reference)
//
#include <hip/hip_runtime.h>
#include <hip/hip_bf16.h>
#include <math.h>

// Cart2Polar: output[b,c,y,x] = bilinear_sample(grid_feat[b,c], gx(y,x), gy(y,x))
// ref_feat is fully overwritten by the reference's scatter -> unused.
// Shapes (fixed by the problem): grid_feat [4,64,480,480] f32, out [4,64,480,360] f32.

#define BB 4
#define CC 64
#define HC 480
#define WC 480
#define HP 480
#define WP 360

__global__ __launch_bounds__(256) void c2p_kernel(const float* __restrict__ g,
                                                  float* __restrict__ out) {
    const int idx = blockIdx.x * 256 + threadIdx.x;   // over B*HP*WP
    constexpr int NPIX = BB * HP * WP;
    if (idx >= NPIX) return;

    const int x = idx % WP;
    const int t = idx / WP;
    const int y = t % HP;
    const int b = t / HP;

    // polar grid math (matches reference, fp32)
    const float PI = 3.14159265358979323846f;
    float theta = PI - (float)x * (2.0f * PI / (float)WP);
    float r = ((float)HP - 0.5f - (float)y + 3.0f) * (1.0f / ((float)HP + 3.0f)) * ((float)WC * 0.5f);
    float s, c;
    __sincosf(theta, &s, &c);
    float index_x = r * c + (float)WC * 0.5f;
    float index_y = r * s + (float)WC * 0.5f;
    // gx = index_x*(Wc-1)/Wc ; gy = index_y*(Hc-1)/Wc  (Hc==Wc==480)
    const float scale = (float)(WC - 1) / (float)WC;
    float gx = index_x * scale;
    float gy = index_y * scale;

    float x0f = floorf(gx);
    float y0f = floorf(gy);
    float wx1 = gx - x0f;
    float wy1 = gy - y0f;
    float wx0 = 1.0f - wx1;
    float wy0 = 1.0f - wy1;

    int x0 = (int)x0f, y0 = (int)y0f;
    int x1 = x0 + 1,  y1 = y0 + 1;

    // zeros-padding: fold validity into the weights, read at clamped index
    float vx0 = (x0 >= 0 && x0 < WC) ? 1.0f : 0.0f;
    float vx1 = (x1 >= 0 && x1 < WC) ? 1.0f : 0.0f;
    float vy0 = (y0 >= 0 && y0 < HC) ? 1.0f : 0.0f;
    float vy1 = (y1 >= 0 && y1 < HC) ? 1.0f : 0.0f;

    float w00 = wx0 * wy0 * vx0 * vy0;
    float w10 = wx1 * wy0 * vx1 * vy0;
    float w01 = wx0 * wy1 * vx0 * vy1;
    float w11 = wx1 * wy1 * vx1 * vy1;

    int cx0 = min(max(x0, 0), WC - 1);
    int cx1 = min(max(x1, 0), WC - 1);
    int cy0 = min(max(y0, 0), HC - 1);
    int cy1 = min(max(y1, 0), HC - 1);

    const int o00 = cy0 * WC + cx0;
    const int o10 = cy0 * WC + cx1;
    const int o01 = cy1 * WC + cx0;
    const int o11 = cy1 * WC + cx1;

    constexpr int HWc = HC * WC;
    constexpr int HWp = HP * WP;

    const float* __restrict__ base = g + (size_t)b * CC * HWc;
    float* __restrict__ ob = out + (size_t)b * CC * HWp + (size_t)y * WP + x;

#pragma unroll 4
    for (int ch = 0; ch < CC; ++ch) {
        const float* __restrict__ p = base + (size_t)ch * HWc;
        float v = p[o00] * w00 + p[o10] * w10 + p[o01] * w01 + p[o11] * w11;
        ob[(size_t)ch * HWp] = v;
    }
}

extern "C" void kernel_launch(void* const* d_in, const int* in_sizes, int n_in,
                              void* d_out, int out_size, void* d_ws, size_t ws_size,
                              hipStream_t stream) {
    const float* grid_feat = (const float*)d_in[0];
    float* out = (float*)d_out;

    constexpr int NPIX = BB * HP * WP;           // 691200
    const int blocks = (NPIX + 255) / 256;       // 2700
    c2p_kernel<<<blocks, 256, 0, stream>>>(grid_feat, out);
}

// Round 2
// 613.067 us; speedup vs baseline: 1.4343x; 1.4343x over previous
//
#include <hip/hip_runtime.h>
#include <hip/hip_bf16.h>
#include <math.h>

// Cart2Polar: output[b,c,y,x] = bilinear_sample(grid_feat[b,c], gx(y,x), gy(y,x))
// ref_feat is fully overwritten by the reference's scatter -> unused.
// Shapes (fixed): grid_feat [4,64,480,480] f32, out [4,64,480,360] f32.

#define BB 4
#define CC 64
#define HC 480
#define WC 480
#define HP 480
#define WP 360

#define NTHREADS 256
#define NPIX (BB * HP * WP)              // 691200
#define NWG   (NPIX / NTHREADS)          // 2700
#define NXCD  8

__global__ __launch_bounds__(NTHREADS) void c2p_kernel(const float* __restrict__ g,
                                                       float* __restrict__ out) {
    // --- bijective XCD-chunked swizzle (m204 variant; 2700 % 8 != 0) ---
    // HW round-robins blockIdx.x % 8 across XCDs; remap so each XCD owns a
    // CONTIGUOUS (b,y) chunk -> adjacent-y gather reuse stays in one L2.
    constexpr int q = NWG / NXCD;        // 337
    constexpr int rr = NWG % NXCD;       // 4
    const int bid  = blockIdx.x;
    const int xcd  = bid % NXCD;
    const int slot = bid / NXCD;
    const int logical = (xcd < rr ? xcd * (q + 1) : rr * (q + 1) + (xcd - rr) * q) + slot;

    const int idx = logical * NTHREADS + threadIdx.x;   // over B*HP*WP

    const int x = idx % WP;
    const int t = idx / WP;
    const int y = t % HP;
    const int b = t / HP;

    // polar grid math (matches reference, fp32)
    const float PI = 3.14159265358979323846f;
    float theta = PI - (float)x * (2.0f * PI / (float)WP);
    float r = ((float)HP - 0.5f - (float)y + 3.0f) * (1.0f / ((float)HP + 3.0f)) * ((float)WC * 0.5f);
    float s, c;
    __sincosf(theta, &s, &c);
    float index_x = r * c + (float)WC * 0.5f;
    float index_y = r * s + (float)WC * 0.5f;
    const float scale = (float)(WC - 1) / (float)WC;
    float gx = index_x * scale;
    float gy = index_y * scale;

    float x0f = floorf(gx);
    float y0f = floorf(gy);
    float wx1 = gx - x0f;
    float wy1 = gy - y0f;
    float wx0 = 1.0f - wx1;
    float wy0 = 1.0f - wy1;

    int x0 = (int)x0f, y0 = (int)y0f;
    int x1 = x0 + 1,  y1 = y0 + 1;

    // zeros-padding: fold validity into weights, read at clamped index
    float vx0 = (x0 >= 0 && x0 < WC) ? 1.0f : 0.0f;
    float vx1 = (x1 >= 0 && x1 < WC) ? 1.0f : 0.0f;
    float vy0 = (y0 >= 0 && y0 < HC) ? 1.0f : 0.0f;
    float vy1 = (y1 >= 0 && y1 < HC) ? 1.0f : 0.0f;

    float w00 = wx0 * wy0 * vx0 * vy0;
    float w10 = wx1 * wy0 * vx1 * vy0;
    float w01 = wx0 * wy1 * vx0 * vy1;
    float w11 = wx1 * wy1 * vx1 * vy1;

    int cx0 = min(max(x0, 0), WC - 1);
    int cx1 = min(max(x1, 0), WC - 1);
    int cy0 = min(max(y0, 0), HC - 1);
    int cy1 = min(max(y1, 0), HC - 1);

    const int o00 = cy0 * WC + cx0;
    const int o10 = cy0 * WC + cx1;
    const int o01 = cy1 * WC + cx0;
    const int o11 = cy1 * WC + cx1;

    constexpr int HWc = HC * WC;
    constexpr int HWp = HP * WP;

    const float* __restrict__ base = g + (size_t)b * CC * HWc;
    float* __restrict__ ob = out + (size_t)b * CC * HWp + (size_t)y * WP + x;

#pragma unroll 8
    for (int ch = 0; ch < CC; ++ch) {
        const float* __restrict__ p = base + (size_t)ch * HWc;
        float v = p[o00] * w00 + p[o10] * w10 + p[o01] * w01 + p[o11] * w11;
        // streaming store: output has zero reuse; keep it out of L2 so the
        // gather annulus working set stays resident
        __builtin_nontemporal_store(v, &ob[(size_t)ch * HWp]);
    }
}

extern "C" void kernel_launch(void* const* d_in, const int* in_sizes, int n_in,
                              void* d_out, int out_size, void* d_ws, size_t ws_size,
                              hipStream_t stream) {
    const float* grid_feat = (const float*)d_in[0];
    float* out = (float*)d_out;
    c2p_kernel<<<NWG, NTHREADS, 0, stream>>>(grid_feat, out);
}

// Round 3
// 430.671 us; speedup vs baseline: 2.0417x; 1.4235x over previous
//
#include <hip/hip_runtime.h>
#include <hip/hip_bf16.h>
#include <math.h>

// Cart2Polar: output[b,c,y,x] = bilinear_sample(grid_feat[b,c], gx(y,x), gy(y,x))
// ref_feat is fully overwritten by the reference's scatter -> unused.
// Shapes (fixed): grid_feat [4,64,480,480] f32, out [4,64,480,360] f32.

#define BB 4
#define CC 64
#define HC 480
#define WC 480
#define HP 480
#define WP 360

#define NTHREADS 256
#define NPIX (BB * HP * WP)              // 691200
#define NWG   (NPIX / NTHREADS)          // 2700
#define NXCD  8
#define CB    16                         // channel batch: 16 ch x 4 corners = 64 loads in flight

__global__ __launch_bounds__(NTHREADS) void c2p_kernel(const float* __restrict__ g,
                                                       float* __restrict__ out) {
    // --- bijective XCD-chunked swizzle (m204 variant; 2700 % 8 != 0) ---
    constexpr int q = NWG / NXCD;        // 337
    constexpr int rr = NWG % NXCD;       // 4
    const int bid  = blockIdx.x;
    const int xcd  = bid % NXCD;
    const int slot = bid / NXCD;
    const int logical = (xcd < rr ? xcd * (q + 1) : rr * (q + 1) + (xcd - rr) * q) + slot;

    const int idx = logical * NTHREADS + threadIdx.x;   // over B*HP*WP

    const int x = idx % WP;
    const int t = idx / WP;
    const int y = t % HP;
    const int b = t / HP;

    // polar grid math (matches reference, fp32)
    const float PI = 3.14159265358979323846f;
    float theta = PI - (float)x * (2.0f * PI / (float)WP);
    float r = ((float)HP - 0.5f - (float)y + 3.0f) * (1.0f / ((float)HP + 3.0f)) * ((float)WC * 0.5f);
    float s, c;
    __sincosf(theta, &s, &c);
    float index_x = r * c + (float)WC * 0.5f;
    float index_y = r * s + (float)WC * 0.5f;
    const float scale = (float)(WC - 1) / (float)WC;
    float gx = index_x * scale;
    float gy = index_y * scale;

    float x0f = floorf(gx);
    float y0f = floorf(gy);
    float wx1 = gx - x0f;
    float wy1 = gy - y0f;
    float wx0 = 1.0f - wx1;
    float wy0 = 1.0f - wy1;

    int x0 = (int)x0f, y0 = (int)y0f;
    int x1 = x0 + 1,  y1 = y0 + 1;

    // zeros-padding: fold validity into weights, read at clamped index
    float vx0 = (x0 >= 0 && x0 < WC) ? 1.0f : 0.0f;
    float vx1 = (x1 >= 0 && x1 < WC) ? 1.0f : 0.0f;
    float vy0 = (y0 >= 0 && y0 < HC) ? 1.0f : 0.0f;
    float vy1 = (y1 >= 0 && y1 < HC) ? 1.0f : 0.0f;

    float w00 = wx0 * wy0 * vx0 * vy0;
    float w10 = wx1 * wy0 * vx1 * vy0;
    float w01 = wx0 * wy1 * vx0 * vy1;
    float w11 = wx1 * wy1 * vx1 * vy1;

    int cx0 = min(max(x0, 0), WC - 1);
    int cx1 = min(max(x1, 0), WC - 1);
    int cy0 = min(max(y0, 0), HC - 1);
    int cy1 = min(max(y1, 0), HC - 1);

    const int o00 = cy0 * WC + cx0;
    const int o10 = cy0 * WC + cx1;
    const int o01 = cy1 * WC + cx0;
    const int o11 = cy1 * WC + cx1;

    constexpr int HWc = HC * WC;
    constexpr int HWp = HP * WP;

    const float* __restrict__ base = g + (size_t)b * CC * HWc;
    float* __restrict__ ob = out + (size_t)b * CC * HWp + (size_t)y * WP + x;

    // Channel batches of CB: issue all 4*CB gathers with STATIC array indices
    // (stays in VGPRs -> compiler pipelines with counted vmcnt), then compute+store.
#pragma unroll
    for (int cb = 0; cb < CC; cb += CB) {
        float a00[CB], a10[CB], a01[CB], a11[CB];
#pragma unroll
        for (int j = 0; j < CB; ++j) {
            const float* __restrict__ p = base + (size_t)(cb + j) * HWc;
            a00[j] = p[o00];
            a10[j] = p[o10];
            a01[j] = p[o01];
            a11[j] = p[o11];
        }
#pragma unroll
        for (int j = 0; j < CB; ++j) {
            float v = a00[j] * w00 + a10[j] * w10 + a01[j] * w01 + a11[j] * w11;
            __builtin_nontemporal_store(v, &ob[(size_t)(cb + j) * HWp]);
        }
    }
}

extern "C" void kernel_launch(void* const* d_in, const int* in_sizes, int n_in,
                              void* d_out, int out_size, void* d_ws, size_t ws_size,
                              hipStream_t stream) {
    const float* grid_feat = (const float*)d_in[0];
    float* out = (float*)d_out;
    c2p_kernel<<<NWG, NTHREADS, 0, stream>>>(grid_feat, out);
}

// Round 4
// 203.363 us; speedup vs baseline: 4.3239x; 2.1177x over previous
//
#include <hip/hip_runtime.h>
#include <hip/hip_bf16.h>
#include <math.h>

// Cart2Polar: output[b,c,y,x] = bilinear_sample(grid_feat[b,c], gx(y,x), gy(y,x))
// ref_feat is fully overwritten by the reference's scatter -> unused.
// Shapes (fixed): grid_feat [4,64,480,480] f32, out [4,64,480,360] f32.
//
// R4 structure: wave footprint = 16y x 4x (compact radial patch -> fewer
// gather transactions); stores transposed through LDS to stay coalesced.

#define BB 4
#define CC 64
#define HC 480
#define WC 480
#define HP 480
#define WP 360

#define TY 16
#define TX 16
#define BYT (HP / TY)                 // 30
#define BXT ((WP + TX - 1) / TX)      // 23 (last tile half-valid)
#define NWG (BB * BYT * BXT)          // 2760 = 8 * 345
#define NXCD 8
#define CPX (NWG / NXCD)              // 345
#define CB 16                         // channels per LDS-transpose batch

__global__ __launch_bounds__(256) void c2p_kernel(const float* __restrict__ g,
                                                  float* __restrict__ out) {
    __shared__ float lds[CB][TY][TX + 1];   // +1 pad: <=2-way bank aliasing (free)

    // --- bijective chunked XCD swizzle (2760 % 8 == 0) ---
    const int bid = blockIdx.x;
    const int logical = (bid & (NXCD - 1)) * CPX + (bid >> 3);
    const int xt = logical % BXT;
    const int t2 = logical / BXT;
    const int yt = t2 % BYT;
    const int b  = t2 / BYT;

    const int tid  = threadIdx.x;
    const int lane = tid & 63;
    const int w    = tid >> 6;
    // gather-phase mapping: wave = 16 consecutive y (radii) x 4 consecutive x
    const int ly = lane >> 2;                 // 0..15
    const int lx = (w << 2) | (lane & 3);     // 0..15
    const int y  = yt * TY + ly;              // < 480 always
    const int x  = xt * TX + lx;              // may be >= 360 in last tile (safe; not stored)

    // polar grid math (matches reference, fp32)
    const float PI = 3.14159265358979323846f;
    float theta = PI - (float)x * (2.0f * PI / (float)WP);
    float r = ((float)HP - 0.5f - (float)y + 3.0f) * (1.0f / ((float)HP + 3.0f)) * ((float)WC * 0.5f);
    float s, c;
    __sincosf(theta, &s, &c);
    float index_x = r * c + (float)WC * 0.5f;
    float index_y = r * s + (float)WC * 0.5f;
    const float scale = (float)(WC - 1) / (float)WC;
    float gx = index_x * scale;
    float gy = index_y * scale;

    float x0f = floorf(gx);
    float y0f = floorf(gy);
    float wx1 = gx - x0f;
    float wy1 = gy - y0f;
    float wx0 = 1.0f - wx1;
    float wy0 = 1.0f - wy1;

    int x0 = (int)x0f, y0 = (int)y0f;
    int x1 = x0 + 1,  y1 = y0 + 1;

    float vx0 = (x0 >= 0 && x0 < WC) ? 1.0f : 0.0f;
    float vx1 = (x1 >= 0 && x1 < WC) ? 1.0f : 0.0f;
    float vy0 = (y0 >= 0 && y0 < HC) ? 1.0f : 0.0f;
    float vy1 = (y1 >= 0 && y1 < HC) ? 1.0f : 0.0f;

    float w00 = wx0 * wy0 * vx0 * vy0;
    float w10 = wx1 * wy0 * vx1 * vy0;
    float w01 = wx0 * wy1 * vx0 * vy1;
    float w11 = wx1 * wy1 * vx1 * vy1;

    int cx0 = min(max(x0, 0), WC - 1);
    int cx1 = min(max(x1, 0), WC - 1);
    int cy0 = min(max(y0, 0), HC - 1);
    int cy1 = min(max(y1, 0), HC - 1);

    const int o00 = cy0 * WC + cx0;
    const int o10 = cy0 * WC + cx1;
    const int o01 = cy1 * WC + cx0;
    const int o11 = cy1 * WC + cx1;

    constexpr int HWc = HC * WC;
    constexpr int HWp = HP * WP;

    const float* __restrict__ base = g + (size_t)b * CC * HWc;

    // store-phase mapping: x-major, 4 rows x 64B per wave-store
    const int srow = tid >> 4;                // 0..15
    const int scol = tid & 15;                // 0..15
    const int sy = yt * TY + srow;
    const int sx = xt * TX + scol;
    const bool sok = (sx < WP);
    float* __restrict__ ob = out + (size_t)b * CC * HWp + (size_t)sy * WP + sx;

    for (int cb = 0; cb < CC; cb += CB) {
        float v[CB];
#pragma unroll
        for (int j = 0; j < CB; ++j) {
            const float* __restrict__ p = base + (size_t)(cb + j) * HWc;
            v[j] = p[o00] * w00 + p[o10] * w10 + p[o01] * w01 + p[o11] * w11;
        }
        __syncthreads();                       // prior batch's LDS reads done
#pragma unroll
        for (int j = 0; j < CB; ++j)
            lds[j][ly][lx] = v[j];
        __syncthreads();
        if (sok) {
#pragma unroll
            for (int j = 0; j < CB; ++j)
                __builtin_nontemporal_store(lds[j][srow][scol], &ob[(size_t)(cb + j) * HWp]);
        }
    }
}

extern "C" void kernel_launch(void* const* d_in, const int* in_sizes, int n_in,
                              void* d_out, int out_size, void* d_ws, size_t ws_size,
                              hipStream_t stream) {
    const float* grid_feat = (const float*)d_in[0];
    float* out = (float*)d_out;
    c2p_kernel<<<NWG, 256, 0, stream>>>(grid_feat, out);
}

// Round 5
// 177.027 us; speedup vs baseline: 4.9671x; 1.1488x over previous
//
#include <hip/hip_runtime.h>
#include <hip/hip_bf16.h>
#include <math.h>

// Cart2Polar: output[b,c,y,x] = bilinear_sample(grid_feat[b,c], gx(y,x), gy(y,x))
// ref_feat is fully overwritten by the reference's scatter -> unused.
// Shapes (fixed): grid_feat [4,64,480,480] f32, out [4,64,480,360] f32.
//
// R5 = R4 tile geometry (16y x 4x wave footprint, LDS-transposed stores)
//    + R3 MLP (explicit statically-indexed corner arrays, 64 loads in flight)
//    + software pipeline (next batch's gathers issued before LDS/store phase).

#define BB 4
#define CC 64
#define HC 480
#define WC 480
#define HP 480
#define WP 360

#define TY 16
#define TX 16
#define BYT (HP / TY)                 // 30
#define BXT ((WP + TX - 1) / TX)      // 23 (last tile x>=360 lanes: computed, not stored)
#define NWG (BB * BYT * BXT)          // 2760 = 8 * 345
#define NXCD 8
#define CPX (NWG / NXCD)              // 345
#define CB 16                         // channels per batch: 4*16 = 64 gathers in flight

__global__ __launch_bounds__(256) void c2p_kernel(const float* __restrict__ g,
                                                  float* __restrict__ out) {
    __shared__ float lds[CB][TY][TX + 1];   // +1 pad: <=2-way bank aliasing (free, m136)

    // --- bijective chunked XCD swizzle (2760 % 8 == 0) ---
    const int bid = blockIdx.x;
    const int logical = (bid & (NXCD - 1)) * CPX + (bid >> 3);
    const int xt = logical % BXT;
    const int t2 = logical / BXT;
    const int yt = t2 % BYT;
    const int b  = t2 / BYT;

    const int tid  = threadIdx.x;
    const int lane = tid & 63;
    const int w    = tid >> 6;
    // gather-phase mapping: wave = 16 consecutive y (radii) x 4 consecutive x
    const int ly = lane >> 2;                 // 0..15
    const int lx = (w << 2) | (lane & 3);     // 0..15
    const int y  = yt * TY + ly;
    const int x  = xt * TX + lx;              // may be >=360 in last tile (not stored)

    // polar grid math (matches reference, fp32)
    const float PI = 3.14159265358979323846f;
    float theta = PI - (float)x * (2.0f * PI / (float)WP);
    float r = ((float)HP - 0.5f - (float)y + 3.0f) * (1.0f / ((float)HP + 3.0f)) * ((float)WC * 0.5f);
    float s, c;
    __sincosf(theta, &s, &c);
    float index_x = r * c + (float)WC * 0.5f;
    float index_y = r * s + (float)WC * 0.5f;
    const float scale = (float)(WC - 1) / (float)WC;
    float gx = index_x * scale;
    float gy = index_y * scale;

    float x0f = floorf(gx);
    float y0f = floorf(gy);
    float wx1 = gx - x0f;
    float wy1 = gy - y0f;
    float wx0 = 1.0f - wx1;
    float wy0 = 1.0f - wy1;

    int x0 = (int)x0f, y0 = (int)y0f;
    int x1 = x0 + 1,  y1 = y0 + 1;

    float vx0 = (x0 >= 0 && x0 < WC) ? 1.0f : 0.0f;
    float vx1 = (x1 >= 0 && x1 < WC) ? 1.0f : 0.0f;
    float vy0 = (y0 >= 0 && y0 < HC) ? 1.0f : 0.0f;
    float vy1 = (y1 >= 0 && y1 < HC) ? 1.0f : 0.0f;

    float w00 = wx0 * wy0 * vx0 * vy0;
    float w10 = wx1 * wy0 * vx1 * vy0;
    float w01 = wx0 * wy1 * vx0 * vy1;
    float w11 = wx1 * wy1 * vx1 * vy1;

    int cx0 = min(max(x0, 0), WC - 1);
    int cx1 = min(max(x1, 0), WC - 1);
    int cy0 = min(max(y0, 0), HC - 1);
    int cy1 = min(max(y1, 0), HC - 1);

    const int o00 = cy0 * WC + cx0;
    const int o10 = cy0 * WC + cx1;
    const int o01 = cy1 * WC + cx0;
    const int o11 = cy1 * WC + cx1;

    constexpr int HWc = HC * WC;
    constexpr int HWp = HP * WP;

    const float* __restrict__ base = g + (size_t)b * CC * HWc;

    // store-phase mapping: x-major, 16 rows x 64B per wave-store
    const int srow = tid >> 4;                // 0..15
    const int scol = tid & 15;                // 0..15
    const int sy = yt * TY + srow;
    const int sx = xt * TX + scol;
    const bool sok = (sx < WP);
    float* __restrict__ ob = out + (size_t)b * CC * HWp + (size_t)sy * WP + sx;

    // ---- software-pipelined channel batches ----
    float a00[CB], a10[CB], a01[CB], a11[CB];

    // prologue: issue batch 0's 64 gathers
#pragma unroll
    for (int j = 0; j < CB; ++j) {
        const float* __restrict__ p = base + (size_t)j * HWc;
        a00[j] = p[o00];
        a10[j] = p[o10];
        a01[j] = p[o01];
        a11[j] = p[o11];
    }

#pragma unroll
    for (int cb = 0; cb < CC; cb += CB) {
        // consume current batch into v (waits on this batch's vmcnt only)
        float v[CB];
#pragma unroll
        for (int j = 0; j < CB; ++j)
            v[j] = a00[j] * w00 + a10[j] * w10 + a01[j] * w01 + a11[j] * w11;

        // issue NEXT batch's gathers: stay in flight across LDS transpose+stores
        if (cb + CB < CC) {
#pragma unroll
            for (int j = 0; j < CB; ++j) {
                const float* __restrict__ p = base + (size_t)(cb + CB + j) * HWc;
                a00[j] = p[o00];
                a10[j] = p[o10];
                a01[j] = p[o01];
                a11[j] = p[o11];
            }
        }

        __syncthreads();                       // prior batch's LDS reads done
#pragma unroll
        for (int j = 0; j < CB; ++j)
            lds[j][ly][lx] = v[j];
        __syncthreads();
        if (sok) {
#pragma unroll
            for (int j = 0; j < CB; ++j)
                __builtin_nontemporal_store(lds[j][srow][scol], &ob[(size_t)(cb + j) * HWp]);
        }
    }
}

extern "C" void kernel_launch(void* const* d_in, const int* in_sizes, int n_in,
                              void* d_out, int out_size, void* d_ws, size_t ws_size,
                              hipStream_t stream) {
    const float* grid_feat = (const float*)d_in[0];
    float* out = (float*)d_out;
    c2p_kernel<<<NWG, 256, 0, stream>>>(grid_feat, out);
}

// Round 6
// 162.435 us; speedup vs baseline: 5.4133x; 1.0898x over previous
//
#include <hip/hip_runtime.h>
#include <hip/hip_bf16.h>
#include <math.h>

// Cart2Polar: output[b,c,y,x] = bilinear_sample(grid_feat[b,c], gx(y,x), gy(y,x))
// ref_feat is fully overwritten by the reference's scatter -> unused.
// Shapes (fixed): grid_feat [4,64,480,480] f32, out [4,64,480,360] f32.
//
// R6 = R5 (16y x 4x wave footprint, LDS-transposed stores, SW pipeline)
//    + paired float2 corner loads (geometry proof: gx,gy in [0.24,478.8],
//      so x0 in [0,478], y0 in [0,478] -> no clamping, no zero-padding,
//      (x0,x0+1) always contiguous -> one dwordx2 per row-pair of corners)
//    + channel-split x2 (32 ch/block, 5520 blocks) for latency-hiding TLP.

#define BB 4
#define CC 64
#define HC 480
#define WC 480
#define HP 480
#define WP 360

#define TY 16
#define TX 16
#define BYT (HP / TY)                  // 30
#define BXT ((WP + TX - 1) / TX)       // 23 (last tile x>=360 lanes: computed, not stored)
#define CSPLIT 2
#define CCB (CC / CSPLIT)              // 32 channels per block
#define NWG (BB * BYT * BXT * CSPLIT)  // 5520 = 8 * 690
#define NXCD 8
#define CPX (NWG / NXCD)               // 690
#define CB 16                          // channels per LDS batch (2 batches/block)

typedef float f2a __attribute__((ext_vector_type(2), aligned(4)));

__global__ __launch_bounds__(256) void c2p_kernel(const float* __restrict__ g,
                                                  float* __restrict__ out) {
    __shared__ float lds[CB][TY][TX + 1];   // +1 pad: conflict-free scalar r/w

    // --- bijective chunked XCD swizzle (5520 % 8 == 0) ---
    const int bid = blockIdx.x;
    const int logical = (bid & (NXCD - 1)) * CPX + (bid >> 3);
    // channel-half fastest -> both halves of a tile stay on one XCD chunk
    const int h  = logical & (CSPLIT - 1);
    const int t1 = logical >> 1;
    const int xt = t1 % BXT;
    const int t2 = t1 / BXT;
    const int yt = t2 % BYT;
    const int b  = t2 / BYT;

    const int tid  = threadIdx.x;
    const int lane = tid & 63;
    const int w    = tid >> 6;
    // gather-phase mapping: wave = 16 consecutive y (radii) x 4 consecutive x
    const int ly = lane >> 2;                 // 0..15
    const int lx = (w << 2) | (lane & 3);     // 0..15
    const int y  = yt * TY + ly;
    const int x  = xt * TX + lx;              // may be >=360 in last tile (not stored)

    // polar grid math (matches reference, fp32)
    const float PI = 3.14159265358979323846f;
    float theta = PI - (float)x * (2.0f * PI / (float)WP);
    float r = ((float)HP - 0.5f - (float)y + 3.0f) * (1.0f / ((float)HP + 3.0f)) * ((float)WC * 0.5f);
    float s, c;
    __sincosf(theta, &s, &c);
    float index_x = r * c + (float)WC * 0.5f;
    float index_y = r * s + (float)WC * 0.5f;
    const float scale = (float)(WC - 1) / (float)WC;
    float gx = index_x * scale;
    float gy = index_y * scale;

    float x0f = floorf(gx);
    float y0f = floorf(gy);
    float wx1 = gx - x0f;
    float wy1 = gy - y0f;
    float wx0 = 1.0f - wx1;
    float wy0 = 1.0f - wy1;

    // proven in-bounds for this geometry: x0,y0 in [0,478] -> no clamp/validity
    const int x0 = (int)x0f;
    const int y0 = (int)y0f;

    const float w00 = wx0 * wy0;
    const float w10 = wx1 * wy0;
    const float w01 = wx0 * wy1;
    const float w11 = wx1 * wy1;

    const int o0 = y0 * WC + x0;     // row y0, cols (x0, x0+1) as one float2
    const int o1 = o0 + WC;          // row y0+1

    constexpr int HWc = HC * WC;
    constexpr int HWp = HP * WP;

    const float* __restrict__ base = g + ((size_t)b * CC + h * CCB) * HWc;

    // store-phase mapping: x-major, 16 rows x 64B per wave-store
    const int srow = tid >> 4;                // 0..15
    const int scol = tid & 15;                // 0..15
    const int sy = yt * TY + srow;
    const int sx = xt * TX + scol;
    const bool sok = (sx < WP);
    float* __restrict__ ob = out + ((size_t)b * CC + h * CCB) * HWp + (size_t)sy * WP + sx;

    // ---- software-pipelined channel batches (2 per block) ----
    f2a a0[CB], a1[CB];

    // prologue: issue batch 0's 32 paired gathers
#pragma unroll
    for (int j = 0; j < CB; ++j) {
        const float* __restrict__ p = base + (size_t)j * HWc;
        a0[j] = *(const f2a*)(p + o0);
        a1[j] = *(const f2a*)(p + o1);
    }

#pragma unroll
    for (int cb = 0; cb < CCB; cb += CB) {
        float v[CB];
#pragma unroll
        for (int j = 0; j < CB; ++j)
            v[j] = a0[j].x * w00 + a0[j].y * w10 + a1[j].x * w01 + a1[j].y * w11;

        // issue NEXT batch's gathers: stay in flight across LDS transpose+stores
        if (cb + CB < CCB) {
#pragma unroll
            for (int j = 0; j < CB; ++j) {
                const float* __restrict__ p = base + (size_t)(cb + CB + j) * HWc;
                a0[j] = *(const f2a*)(p + o0);
                a1[j] = *(const f2a*)(p + o1);
            }
        }

        __syncthreads();                       // prior batch's LDS reads done
#pragma unroll
        for (int j = 0; j < CB; ++j)
            lds[j][ly][lx] = v[j];
        __syncthreads();
        if (sok) {
#pragma unroll
            for (int j = 0; j < CB; ++j)
                __builtin_nontemporal_store(lds[j][srow][scol], &ob[(size_t)(cb + j) * HWp]);
        }
    }
}

extern "C" void kernel_launch(void* const* d_in, const int* in_sizes, int n_in,
                              void* d_out, int out_size, void* d_ws, size_t ws_size,
                              hipStream_t stream) {
    const float* grid_feat = (const float*)d_in[0];
    float* out = (float*)d_out;
    c2p_kernel<<<NWG, 256, 0, stream>>>(grid_feat, out);
}